// Round 15
// baseline (624.778 us; speedup 1.0000x reference)
//
#include <hip/hip_runtime.h>
#include <hip/hip_bf16.h>
#include <math.h>

#define BATCH 4
#define MMDIM 256
#define NNDIM 256
#define CH 64
#define NMODES 32
#define HID 128
#define NLAYERS 4
#define XPLANE 16777216L   // ushorts per hi/lo plane of an xbf tensor

typedef __attribute__((ext_vector_type(8))) short bfrag;    // 8 bf16
typedef __attribute__((ext_vector_type(8))) ushort u16x8;   // 16B
typedef __attribute__((ext_vector_type(4))) float f32x4;

__device__ inline ushort f2bf(float x) {   // RTN-even f32 -> bf16 (setup kernels)
    union { float f; uint u; } v; v.f = x;
    uint r = v.u + 0x7fff + ((v.u >> 16) & 1);
    return (ushort)(r >> 16);
}
__device__ inline float bf2f(ushort h) {
    union { uint u; float f; } v; v.u = (uint)h << 16; return v.f;
}
// fast hi/lo split via HW bf16 cast (hot kernels)
__device__ inline void split(float v, ushort& hi, ushort& lo) {
    __hip_bfloat16 h = __float2bfloat16(v);
    hi = __builtin_bit_cast(ushort, h);
    lo = __builtin_bit_cast(ushort, __float2bfloat16(v - __bfloat162float(h)));
}
__device__ inline ushort f2bf_hw(float v) {
    return __builtin_bit_cast(ushort, __float2bfloat16(v));
}
#define MFMA __builtin_amdgcn_mfma_f32_16x16x32_bf16

// ---------------- setup kernels ----------------

// DCT A-frags: Tf[yt(2)][ks(8)][lane(64)][j(8)] =
//   T[yt*16+(lane&15)][ks*32+(lane>>4)*8+j], hi plane then +8192 lo plane.
__global__ __launch_bounds__(256) void k_Tfrag(ushort* __restrict__ Tf) {
    int idx = blockIdx.x * 256 + threadIdx.x;   // 8192
    int j = idx & 7, lane = (idx >> 3) & 63, ks = (idx >> 9) & 7, yt = idx >> 12;
    int k = yt * 16 + (lane & 15);
    int n = ks * 32 + ((lane >> 4) << 3) + j;
    double v = cos(M_PI * (n + 0.5) * (double)k / 256.0) * 0.08838834764831845;
    if (k == 0) v *= 0.7071067811865476;
    float vf = (float)v;
    ushort hh = f2bf(vf);
    Tf[idx] = hh; Tf[idx + 8192] = f2bf(vf - bf2f(hh));
}

// iDCT A-frags: Ttf[at(16)][lane(64)][j(8)] = T[(lane>>4)*8+j][at*16+(lane&15)]
__global__ __launch_bounds__(256) void k_Ttfrag(ushort* __restrict__ Ttf) {
    int idx = blockIdx.x * 256 + threadIdx.x;   // 8192
    int j = idx & 7, lane = (idx >> 3) & 63, at = idx >> 9;
    int k = ((lane >> 4) << 3) + j;
    int n = at * 16 + (lane & 15);
    double v = cos(M_PI * (n + 0.5) * (double)k / 256.0) * 0.08838834764831845;
    if (k == 0) v *= 0.7071067811865476;
    float vf = (float)v;
    ushort hh = f2bf(vf);
    Ttf[idx] = hh; Ttf[idx + 8192] = f2bf(vf - bf2f(hh));
}

// fw0|fw1: [L][64][64][32] (l,i,o,y) -> w0t|w1t: [L][32][64][64] (l,y,i,o); one launch for both
__global__ __launch_bounds__(256) void k_wt(const float* __restrict__ fw0, const float* __restrict__ fw1,
                                            float* __restrict__ wt01) {
    int idx = blockIdx.x * 256 + threadIdx.x;   // over 2*524288
    const float* fw = (idx < 524288) ? fw0 : fw1;
    int i2 = idx & 524287;
    int l = i2 >> 17, r = i2 & 131071;
    int y = r >> 12, i = (r >> 6) & 63, o = r & 63;
    wt01[idx] = fw[((l * 64 + i) * 64 + o) * 32 + y];
}

// FF weight frags (validated R3): [l][nt][ks][lane][jj]
__global__ __launch_bounds__(256) void k_wfrag(const float* __restrict__ W,
                                               ushort* __restrict__ hi, ushort* __restrict__ lo,
                                               int N, int K) {
    int idx = blockIdx.x * 256 + threadIdx.x;
    int per_l = N * K;
    int l = idx / per_l, r = idx % per_l;
    int jj = r & 7, lane = (r >> 3) & 63;
    int ks = (r >> 9) % (K >> 5);
    int nt = r / (512 * (K >> 5));
    int row = nt * 16 + (lane & 15);
    int col = ks * 32 + ((lane >> 4) << 3) + jj;
    float v = W[(long)l * per_l + row * K + col];
    ushort h = f2bf(v);
    hi[idx] = h;
    lo[idx] = f2bf(v - bf2f(h));
}

__global__ void k_head(const float* __restrict__ W_o1, const float* __restrict__ b_o1,
                       const float* __restrict__ W_o2, const float* __restrict__ b_o2,
                       float* __restrict__ Weff, float* __restrict__ beff) {
    int c = threadIdx.x;
    float acc = 0.f;
    for (int j = 0; j < 128; j++) acc += W_o2[j] * W_o1[j * 64 + c];
    Weff[c] = acc;
    if (c == 0) {
        float bb = 0.f;
        for (int j = 0; j < 128; j++) bb += W_o2[j] * b_o1[j];
        beff[0] = bb + b_o2[0];
    }
}

// Fused input projection -> bf16 hi/lo in [b][m][c][n] layout.
__global__ __launch_bounds__(256) void k_inproj_bf(const float* __restrict__ xin,
                                                   const float* __restrict__ W_in,
                                                   const float* __restrict__ b_in,
                                                   ushort* __restrict__ xbf) {
    __shared__ __align__(16) ushort tile[2][64][72];
    int t = threadIdx.x;
    int bid = blockIdx.x;
    int b = bid >> 10, m = (bid >> 2) & 255, n0 = (bid & 3) * 64;
    int c = t & 63, ng = t >> 6;
    long pbase = (long)(b * 256 + m) * 256 + n0;
    float w[12];
#pragma unroll
    for (int d = 0; d < 12; d++) w[d] = W_in[c * 12 + d];
    float bc = b_in[c];
#pragma unroll 4
    for (int i = 0; i < 16; i++) {
        int nl = ng * 16 + i;
        const float* xr = xin + (pbase + nl) * 12;
        float acc = bc;
#pragma unroll
        for (int d = 0; d < 12; d++) acc += xr[d] * w[d];
        ushort hh, ll;
        split(acc, hh, ll);
        tile[0][c][nl] = hh;
        tile[1][c][nl] = ll;
    }
    __syncthreads();
    int c2 = t >> 2, ch = t & 3;
#pragma unroll
    for (int pl = 0; pl < 2; pl++) {
        const ushort* s = &tile[pl][c2][ch * 16];
        u16x8 v0 = *(const u16x8*)s;
        u16x8 v1 = *(const u16x8*)(s + 8);
        ushort* dst = xbf + (long)pl * XPLANE + ((long)(b * 256 + m) * 64 + c2) * 256 + n0 + ch * 16;
        *(u16x8*)dst = v0; *(u16x8*)(dst + 8) = v1;
    }
}

// bf16 transpose: xbf_y [b][m][c][n] -> xbf_x [b][n][c][m].
__global__ __launch_bounds__(256) void k_tx(const ushort* __restrict__ src, ushort* __restrict__ dst) {
    __shared__ __align__(16) ushort tl[64][72];
    int t = threadIdx.x;
    int bid = blockIdx.x;
    int ntile = bid & 3, mt = (bid >> 2) & 3, c = (bid >> 4) & 63, b = (bid >> 10) & 3, pl = bid >> 12;
    int m0 = mt * 64, n0 = ntile * 64;
    const ushort* sp = src + (long)pl * XPLANE;
    ushort* dp = dst + (long)pl * XPLANE;
    {
        int row = t >> 2, ch = (t & 3) * 16;
        const ushort* p = sp + ((long)(b * 256 + m0 + row) * 64 + c) * 256 + n0 + ch;
        u16x8 v0 = *(const u16x8*)p;
        u16x8 v1 = *(const u16x8*)(p + 8);
#pragma unroll
        for (int k = 0; k < 8; k++) tl[ch + k][row] = v0[k];
#pragma unroll
        for (int k = 0; k < 8; k++) tl[ch + 8 + k][row] = v1[k];
    }
    __syncthreads();
    {
        int nrow = t >> 2, mch = (t & 3) * 16;
        const ushort* s = &tl[nrow][mch];
        u16x8 v0 = *(const u16x8*)s;
        u16x8 v1 = *(const u16x8*)(s + 8);
        ushort* p = dp + ((long)(b * 256 + n0 + nrow) * 64 + c) * 256 + m0 + mch;
        *(u16x8*)p = v0; *(u16x8*)(p + 8) = v1;
    }
}

// ---------------- merged spectral kernel ----------------
// grid 1024: blocks 0..511 = y-path: DCT -> mix -> dump Xm_y[b][m][pl][c][y] (bf16 hi/lo, 8 MB)
//            blocks 512..1023 = x-path: DCT -> mix -> iDCT -> h_x[b][n][a=m][c] bf16
__global__ __launch_bounds__(512) void k_spec(const ushort* __restrict__ xbf_y,
                                              const ushort* __restrict__ xbf_x,
                                              const ushort* __restrict__ Tf,
                                              const ushort* __restrict__ Ttf,
                                              const float* __restrict__ wt_y,
                                              const float* __restrict__ wt_x,
                                              ushort* __restrict__ xmy,
                                              ushort* __restrict__ hx) {
    __shared__ float Xs[2][32][68];                    // 17.4 KB
    __shared__ __align__(16) ushort Xmb[2][2][64][40]; // [s][pl][o][y] 20.5 KB
    int t = threadIdx.x;
    int lane = t & 63, wv = t >> 6, l15 = lane & 15, l4 = lane >> 4;
    int bid = blockIdx.x;
    int xpath = bid >> 9;               // 0 = y-path, 1 = x-path (block-uniform)
    int lb = bid & 511;
    int fp = lb & 127, b = lb >> 7;
    int s_ = wv >> 2;
    const ushort* xbf = xpath ? xbf_x : xbf_y;
    const float* wt = xpath ? wt_x : wt_y;

    // ---- DCT (MFMA) ----
    {
        const ushort* xb = xbf + ((long)(b * 256 + fp * 2 + s_)) * 16384;
        f32x4 a0 = {0.f, 0.f, 0.f, 0.f}, a1 = {0.f, 0.f, 0.f, 0.f};
        int c0 = (wv & 3) * 16;
#pragma unroll
        for (int ks = 0; ks < 8; ks++) {
            const ushort* bp = xb + (c0 + l15) * 256 + ks * 32 + l4 * 8;
            bfrag bhi = *(const bfrag*)bp;
            bfrag blo = *(const bfrag*)(bp + XPLANE);
            const ushort* ap0 = Tf + (long)((0 * 8 + ks) * 64 + lane) * 8;
            const ushort* ap1 = Tf + (long)((1 * 8 + ks) * 64 + lane) * 8;
            bfrag a0h = *(const bfrag*)ap0, a0l = *(const bfrag*)(ap0 + 8192);
            bfrag a1h = *(const bfrag*)ap1, a1l = *(const bfrag*)(ap1 + 8192);
            a0 = MFMA(a0h, bhi, a0, 0, 0, 0);
            a0 = MFMA(a0h, blo, a0, 0, 0, 0);
            a0 = MFMA(a0l, bhi, a0, 0, 0, 0);
            a1 = MFMA(a1h, bhi, a1, 0, 0, 0);
            a1 = MFMA(a1h, blo, a1, 0, 0, 0);
            a1 = MFMA(a1l, bhi, a1, 0, 0, 0);
        }
#pragma unroll
        for (int r = 0; r < 4; r++) {
            Xs[s_][l4 * 4 + r][c0 + l15] = a0[r];
            Xs[s_][16 + l4 * 4 + r][c0 + l15] = a1[r];
        }
    }
    __syncthreads();

    // ---- mix (VALU); weight load amortized over both slabs ----
    {
        int og = t & 15, y = t >> 4;   // y in 0..31
        const float* wb = wt + (long)y * 4096 + og * 4;
        f32x4 A0 = {0.f, 0.f, 0.f, 0.f}, A1 = {0.f, 0.f, 0.f, 0.f};
#pragma unroll 8
        for (int i = 0; i < 64; i++) {
            float4 wv4 = *(const float4*)(wb + i * 64);
            float x0 = Xs[0][y][i];
            float x1 = Xs[1][y][i];
            A0.x += x0 * wv4.x; A0.y += x0 * wv4.y; A0.z += x0 * wv4.z; A0.w += x0 * wv4.w;
            A1.x += x1 * wv4.x; A1.y += x1 * wv4.y; A1.z += x1 * wv4.z; A1.w += x1 * wv4.w;
        }
#pragma unroll
        for (int e = 0; e < 4; e++) {
            ushort hh, ll;
            split(A0[e], hh, ll);
            Xmb[0][0][og * 4 + e][y] = hh;
            Xmb[0][1][og * 4 + e][y] = ll;
            split(A1[e], hh, ll);
            Xmb[1][0][og * 4 + e][y] = hh;
            Xmb[1][1][og * 4 + e][y] = ll;
        }
    }
    __syncthreads();

    if (!xpath) {
        // ---- y-path: dump Xmb to global Xm_y[b][m=f][pl][c][y] (8 KB/slab) ----
        int r = t & 255, s2 = t >> 8;
        int pl = r >> 7, c = (r >> 1) & 63, yh = (r & 1) * 16;
        long f2 = fp * 2 + s2;
        ushort* dst = xmy + ((long)(b * 256 + f2) * 2 + pl) * 2048 + c * 32 + yh;
        *(u16x8*)dst = *(const u16x8*)&Xmb[s2][pl][c][yh];
        *(u16x8*)(dst + 8) = *(const u16x8*)&Xmb[s2][pl][c][yh + 8];
        return;
    }

    // ---- x-path iDCT (MFMA) -> h_x[b][n=f][a=m][c] bf16, coalesced ----
    bfrag vbh[4], vbl[4];
#pragma unroll
    for (int ot = 0; ot < 4; ot++) {
        vbh[ot] = *(const bfrag*)(&Xmb[s_][0][ot * 16 + l15][l4 * 8]);
        vbl[ot] = *(const bfrag*)(&Xmb[s_][1][ot * 16 + l15][l4 * 8]);
    }
    int f = fp * 2 + s_;
#pragma unroll
    for (int ai = 0; ai < 4; ai++) {
        int at = (wv & 3) * 4 + ai;
        const ushort* ap = Ttf + (long)(at * 64 + lane) * 8;
        bfrag th = *(const bfrag*)ap, tl_ = *(const bfrag*)(ap + 8192);
#pragma unroll
        for (int ot = 0; ot < 4; ot++) {
            f32x4 acc = {0.f, 0.f, 0.f, 0.f};
            acc = MFMA(th, vbh[ot], acc, 0, 0, 0);
            acc = MFMA(th, vbl[ot], acc, 0, 0, 0);
            acc = MFMA(tl_, vbh[ot], acc, 0, 0, 0);
            int arow = at * 16 + l4 * 4;
            ushort* op = hx + (long)b * 4194304 + (long)f * 16384 + (long)arow * 64 + ot * 16 + l15;
#pragma unroll
            for (int r = 0; r < 4; r++) op[r * 64] = f2bf_hw(acc[r]);
        }
    }
}

// ---------------- FFN via bf16x3 MFMA; h_y reconstructed in-kernel via iDCT ----------------
// LDS union: hyt [64][68] f32 (phase 0 .. frag-build) overlaps Asb [2][64][136] ushort
// (GEMM1 output .. epilogue). Total 34.8 KB -> 4 blocks/CU (R14 was 52 KB -> 3).
#define ASW 136   // ushort row stride (128 + 8 pad)
__global__ __launch_bounds__(256) void k_ff(const ushort* __restrict__ xmy,
                                            const ushort* __restrict__ hx,
                                            const ushort* __restrict__ Ttf,
                                            ushort* __restrict__ xbfw,
                                            const ushort* __restrict__ W1hi, const ushort* __restrict__ W1lo,
                                            const float* __restrict__ b1,
                                            const ushort* __restrict__ W2hi, const ushort* __restrict__ W2lo,
                                            const float* __restrict__ b2,
                                            const float* __restrict__ Weff, const float* __restrict__ beff,
                                            float* __restrict__ out, int last) {
    __shared__ __align__(16) ushort smem[2 * 64 * ASW];   // 34.8 KB union
    float* hyt = (float*)&smem[0];                         // [64][68] f32 (17.4 KB) while live
    int t = threadIdx.x;
    int lane = t & 63, wv = t >> 6;
    int l15 = lane & 15, l4 = lane >> 4;
    long p0 = (long)blockIdx.x * 64;
    int b = (int)(p0 >> 16), m = (int)((p0 >> 8) & 255), n0 = (int)(p0 & 255);

    // ---- phase 0: iDCT-y -> hyt (wave wv owns n-rows wv*16..+15) ----
    {
        const ushort* xm = xmy + ((long)(b * 256 + m) * 2) * 2048;
        int at = (n0 >> 4) + wv;
        const ushort* ap = Ttf + (long)(at * 64 + lane) * 8;
        bfrag th = *(const bfrag*)ap, tl_ = *(const bfrag*)(ap + 8192);
#pragma unroll
        for (int ot = 0; ot < 4; ot++) {
            const ushort* xp = xm + (ot * 16 + l15) * 32 + l4 * 8;
            bfrag xh = *(const bfrag*)xp;
            bfrag xl = *(const bfrag*)(xp + 2048);
            f32x4 acc = {0.f, 0.f, 0.f, 0.f};
            acc = MFMA(th, xh, acc, 0, 0, 0);
            acc = MFMA(th, xl, acc, 0, 0, 0);
            acc = MFMA(tl_, xh, acc, 0, 0, 0);
#pragma unroll
            for (int r = 0; r < 4; r++)
                hyt[(wv * 16 + l4 * 4 + r) * 68 + ot * 16 + l15] = acc[r];
        }
    }
    __syncthreads();

    // ---- build GEMM1 A-fragments into registers (hyt consumed here) ----
    bfrag ahi_[2], alo_[2];
#pragma unroll
    for (int ks = 0; ks < 2; ks++) {
        int px = wv * 16 + l15;
        const float* hp = &hyt[px * 68 + ks * 32 + l4 * 8];
        float4 h0 = *(const float4*)hp;
        float4 h1 = *(const float4*)(hp + 4);
        long xoff = ((long)b * 65536 + (long)(n0 + px) * 256 + m) * 64 + ks * 32 + l4 * 8;
        u16x8 hx8 = *(const u16x8*)(hx + xoff);
#pragma unroll
        for (int j = 0; j < 8; j++) {
            float v = ((j < 4) ? (&h0.x)[j] : (&h1.x)[j - 4]) + bf2f(hx8[j]);
            ushort hh, ll;
            split(v, hh, ll);
            ahi_[ks][j] = (short)hh; alo_[ks][j] = (short)ll;
        }
    }
    __syncthreads();   // hyt dead; smem becomes Asb

    // ---- GEMM1 MFMAs (3-MFMA interleave per (ks,nt), unchanged) ----
    f32x4 acc1[8];
#pragma unroll
    for (int nt = 0; nt < 8; nt++) acc1[nt] = (f32x4){0.f, 0.f, 0.f, 0.f};
#pragma unroll
    for (int ks = 0; ks < 2; ks++) {
#pragma unroll
        for (int nt = 0; nt < 8; nt++) {
            long off = (long)((nt * 2 + ks) * 64 + lane) * 8;
            bfrag bhi = *(const bfrag*)(W1hi + off);
            bfrag blo = *(const bfrag*)(W1lo + off);
            acc1[nt] = MFMA(ahi_[ks], bhi, acc1[nt], 0, 0, 0);
            acc1[nt] = MFMA(ahi_[ks], blo, acc1[nt], 0, 0, 0);
            acc1[nt] = MFMA(alo_[ks], bhi, acc1[nt], 0, 0, 0);
        }
    }
    // bias + relu + hi/lo split -> Asb
#pragma unroll
    for (int nt = 0; nt < 8; nt++) {
        float bj = b1[nt * 16 + l15];
        int j = nt * 16 + l15;
#pragma unroll
        for (int r = 0; r < 4; r++) {
            float v = fmaxf(acc1[nt][r] + bj, 0.f);
            int px = wv * 16 + l4 * 4 + r;
            ushort hh, ll;
            split(v, hh, ll);
            smem[(0 * 64 + px) * ASW + j] = hh;
            smem[(1 * 64 + px) * ASW + j] = ll;
        }
    }
    __syncthreads();   // REQUIRED: LDS write->read ordering (R12 race without it)

    // GEMM2: O = A @ W2^T  (A-frags straight from LDS, no conversion)
    f32x4 acc2[4];
#pragma unroll
    for (int nt = 0; nt < 4; nt++) acc2[nt] = (f32x4){0.f, 0.f, 0.f, 0.f};
#pragma unroll
    for (int ks = 0; ks < 4; ks++) {
        int px = wv * 16 + l15;
        bfrag ahi = *(const bfrag*)(&smem[(0 * 64 + px) * ASW + ks * 32 + l4 * 8]);
        bfrag alo = *(const bfrag*)(&smem[(1 * 64 + px) * ASW + ks * 32 + l4 * 8]);
#pragma unroll
        for (int nt = 0; nt < 4; nt++) {
            long off = (long)((nt * 4 + ks) * 64 + lane) * 8;
            bfrag bhi = *(const bfrag*)(W2hi + off);
            bfrag blo = *(const bfrag*)(W2lo + off);
            acc2[nt] = MFMA(ahi, bhi, acc2[nt], 0, 0, 0);
            acc2[nt] = MFMA(ahi, blo, acc2[nt], 0, 0, 0);
            acc2[nt] = MFMA(alo, bhi, acc2[nt], 0, 0, 0);
        }
    }

    if (last) {
        float be = beff[0];
#pragma unroll
        for (int r = 0; r < 4; r++) {
            float v = 0.f;
#pragma unroll
            for (int nt = 0; nt < 4; nt++) {
                int c = nt * 16 + l15;
                v += (acc2[nt][r] + b2[c]) * Weff[c];
            }
            v += __shfl_xor(v, 1, 64);
            v += __shfl_xor(v, 2, 64);
            v += __shfl_xor(v, 4, 64);
            v += __shfl_xor(v, 8, 64);
            if (l15 == 0) out[p0 + wv * 16 + l4 * 4 + r] = v + be;
        }
    } else {
        __syncthreads();   // all waves done with their Asb rows
        ushort* tile = &smem[0];   // reuse as [2][64][72] x-tile (18.4 KB)
        int c2 = t >> 2, ch = t & 3;
        // stage residual coalesced into tile
#pragma unroll
        for (int pl = 0; pl < 2; pl++) {
            const ushort* src = xbfw + (long)pl * XPLANE + ((long)(b * 256 + m) * 64 + c2) * 256 + n0 + ch * 16;
            u16x8 v0 = *(const u16x8*)src;
            u16x8 v1 = *(const u16x8*)(src + 8);
            ushort* d = tile + (pl * 64 + c2) * 72 + ch * 16;
            *(u16x8*)d = v0; *(u16x8*)(d + 8) = v1;
        }
        __syncthreads();
        // per-thread RMW in LDS (each (c,nl) owned by exactly one thread)
#pragma unroll
        for (int nt = 0; nt < 4; nt++) {
            int c = nt * 16 + l15;
            float bc = b2[c];
#pragma unroll
            for (int r = 0; r < 4; r++) {
                int nl = wv * 16 + l4 * 4 + r;
                float res = bf2f(tile[(0 * 64 + c) * 72 + nl]) + bf2f(tile[(1 * 64 + c) * 72 + nl]);
                float v = res + acc2[nt][r] + bc;
                ushort hh, ll;
                split(v, hh, ll);
                tile[(0 * 64 + c) * 72 + nl] = hh;
                tile[(1 * 64 + c) * 72 + nl] = ll;
            }
        }
        __syncthreads();
        // coalesced store back to xbf_y
#pragma unroll
        for (int pl = 0; pl < 2; pl++) {
            const ushort* s = tile + (pl * 64 + c2) * 72 + ch * 16;
            u16x8 v0 = *(const u16x8*)s;
            u16x8 v1 = *(const u16x8*)(s + 8);
            ushort* dst = xbfw + (long)pl * XPLANE + ((long)(b * 256 + m) * 64 + c2) * 256 + n0 + ch * 16;
            *(u16x8*)dst = v0; *(u16x8*)(dst + 8) = v1;
        }
    }
}

// ---------------- launcher ----------------

extern "C" void kernel_launch(void* const* d_in, const int* in_sizes, int n_in,
                              void* d_out, int out_size, void* d_ws, size_t ws_size,
                              hipStream_t stream) {
    const float* x_in = (const float*)d_in[0];
    const float* W_in = (const float*)d_in[1];
    const float* b_in = (const float*)d_in[2];
    const float* fw0  = (const float*)d_in[3];
    const float* fw1  = (const float*)d_in[4];
    const float* ffW1 = (const float*)d_in[5];
    const float* ffb1 = (const float*)d_in[6];
    const float* ffW2 = (const float*)d_in[7];
    const float* ffb2 = (const float*)d_in[8];
    const float* W_o1 = (const float*)d_in[9];
    const float* b_o1 = (const float*)d_in[10];
    const float* W_o2 = (const float*)d_in[11];
    const float* b_o2 = (const float*)d_in[12];
    float* out = (float*)d_out;

    // workspace layout: ~172 MiB
    float* ws   = (float*)d_ws;
    float* w0t  = ws;                     // 524288
    float* w1t  = w0t + 524288;           // 524288
    float* Weff = w1t + 524288;           // 64
    float* beff = Weff + 64;              // 64
    ushort* xmy = (ushort*)(beff + 64);         // 4194304 ushorts (8 MB): [b][m][pl][c][y]
    ushort* h_x = xmy + 4194304;                // 16777216 ushorts (32 MB)
    ushort* Tfrag  = h_x + 16777216;            // 16384
    ushort* Ttfrag = Tfrag + 16384;             // 16384
    ushort* W1f_hi = Ttfrag + 16384;            // 32768
    ushort* W1f_lo = W1f_hi + 32768;
    ushort* W2f_hi = W1f_lo + 32768;
    ushort* W2f_lo = W2f_hi + 32768;
    ushort* xbf_y  = W2f_lo + 32768;            // 2*16777216 (64 MB)
    ushort* xbf_x  = xbf_y + 2 * XPLANE;        // 2*16777216 (64 MB)

    k_Tfrag<<<32, 256, 0, stream>>>(Tfrag);
    k_Ttfrag<<<32, 256, 0, stream>>>(Ttfrag);
    k_wt<<<4096, 256, 0, stream>>>(fw0, fw1, w0t);
    k_wfrag<<<(NLAYERS * HID * CH) / 256, 256, 0, stream>>>(ffW1, W1f_hi, W1f_lo, HID, CH);
    k_wfrag<<<(NLAYERS * CH * HID) / 256, 256, 0, stream>>>(ffW2, W2f_hi, W2f_lo, CH, HID);
    k_head<<<1, 64, 0, stream>>>(W_o1, b_o1, W_o2, b_o2, Weff, beff);
    k_inproj_bf<<<4096, 256, 0, stream>>>(x_in, W_in, b_in, xbf_y);

    for (int l = 0; l < NLAYERS; l++) {
        // transpose: xbf_x[b][n][c][m] from current xbf_y
        k_tx<<<8192, 256, 0, stream>>>(xbf_y, xbf_x);
        // merged spectral: y-blocks -> Xm_y (bf16 hi/lo spectral), x-blocks -> h_x (bf16)
        k_spec<<<1024, 512, 0, stream>>>(xbf_y, xbf_x, Tfrag, Ttfrag,
                                         w0t + (long)l * 131072, w1t + (long)l * 131072,
                                         xmy, h_x);
        // FFN (+ in-kernel iDCT-y) + residual (RMW on xbf_y) (+ head on last layer)
        k_ff<<<4096, 256, 0, stream>>>(xmy, h_x, Ttfrag, xbf_y,
            W1f_hi + (long)l * HID * CH, W1f_lo + (long)l * HID * CH,
            ffb1 + (long)l * HID,
            W2f_hi + (long)l * CH * HID, W2f_lo + (long)l * CH * HID,
            ffb2 + (long)l * CH,
            Weff, beff, out, (l == NLAYERS - 1) ? 1 : 0);
    }
}

// Round 16
// 601.845 us; speedup vs baseline: 1.0381x; 1.0381x over previous
//
#include <hip/hip_runtime.h>
#include <hip/hip_bf16.h>
#include <math.h>

#define BATCH 4
#define MMDIM 256
#define NNDIM 256
#define CH 64
#define NMODES 32
#define HID 128
#define NLAYERS 4
#define XPLANE 16777216L   // ushorts per hi/lo plane of an xbf tensor

typedef __attribute__((ext_vector_type(8))) short bfrag;    // 8 bf16
typedef __attribute__((ext_vector_type(8))) ushort u16x8;   // 16B
typedef __attribute__((ext_vector_type(4))) float f32x4;

__device__ inline ushort f2bf(float x) {   // RTN-even f32 -> bf16 (setup kernels)
    union { float f; uint u; } v; v.f = x;
    uint r = v.u + 0x7fff + ((v.u >> 16) & 1);
    return (ushort)(r >> 16);
}
__device__ inline float bf2f(ushort h) {
    union { uint u; float f; } v; v.u = (uint)h << 16; return v.f;
}
// fast hi/lo split via HW bf16 cast (hot kernels)
__device__ inline void split(float v, ushort& hi, ushort& lo) {
    __hip_bfloat16 h = __float2bfloat16(v);
    hi = __builtin_bit_cast(ushort, h);
    lo = __builtin_bit_cast(ushort, __float2bfloat16(v - __bfloat162float(h)));
}
__device__ inline ushort f2bf_hw(float v) {
    return __builtin_bit_cast(ushort, __float2bfloat16(v));
}
#define MFMA __builtin_amdgcn_mfma_f32_16x16x32_bf16

// ---------------- setup kernels ----------------

// Both DCT/iDCT A-frag tables in one launch (grid 64):
//  blocks 0..31 : Tf[yt(2)][ks(8)][lane(64)][j(8)] = T[yt*16+(l&15)][ks*32+(l>>4)*8+j]
//  blocks 32..63: Ttf[at(16)][lane(64)][j(8)]      = T[(l>>4)*8+j][at*16+(l&15)]
// hi plane, then +8192 lo plane.
__global__ __launch_bounds__(256) void k_Tboth(ushort* __restrict__ Tf, ushort* __restrict__ Ttf) {
    int gb = blockIdx.x;
    if (gb < 32) {
        int idx = gb * 256 + threadIdx.x;   // 8192
        int j = idx & 7, lane = (idx >> 3) & 63, ks = (idx >> 9) & 7, yt = idx >> 12;
        int k = yt * 16 + (lane & 15);
        int n = ks * 32 + ((lane >> 4) << 3) + j;
        double v = cos(M_PI * (n + 0.5) * (double)k / 256.0) * 0.08838834764831845;
        if (k == 0) v *= 0.7071067811865476;
        float vf = (float)v;
        ushort hh = f2bf(vf);
        Tf[idx] = hh; Tf[idx + 8192] = f2bf(vf - bf2f(hh));
    } else {
        int idx = (gb - 32) * 256 + threadIdx.x;   // 8192
        int j = idx & 7, lane = (idx >> 3) & 63, at = idx >> 9;
        int k = ((lane >> 4) << 3) + j;
        int n = at * 16 + (lane & 15);
        double v = cos(M_PI * (n + 0.5) * (double)k / 256.0) * 0.08838834764831845;
        if (k == 0) v *= 0.7071067811865476;
        float vf = (float)v;
        ushort hh = f2bf(vf);
        Ttf[idx] = hh; Ttf[idx + 8192] = f2bf(vf - bf2f(hh));
    }
}

// fw0|fw1: [L][64][64][32] (l,i,o,y) -> w0t|w1t: [L][32][64][64] (l,y,i,o); one launch for both
__global__ __launch_bounds__(256) void k_wt(const float* __restrict__ fw0, const float* __restrict__ fw1,
                                            float* __restrict__ wt01) {
    int idx = blockIdx.x * 256 + threadIdx.x;   // over 2*524288
    const float* fw = (idx < 524288) ? fw0 : fw1;
    int i2 = idx & 524287;
    int l = i2 >> 17, r = i2 & 131071;
    int y = r >> 12, i = (r >> 6) & 63, o = r & 63;
    wt01[idx] = fw[((l * 64 + i) * 64 + o) * 32 + y];
}

// FF weight frags (validated R3): [l][nt][ks][lane][jj]
__global__ __launch_bounds__(256) void k_wfrag(const float* __restrict__ W,
                                               ushort* __restrict__ hi, ushort* __restrict__ lo,
                                               int N, int K) {
    int idx = blockIdx.x * 256 + threadIdx.x;
    int per_l = N * K;
    int l = idx / per_l, r = idx % per_l;
    int jj = r & 7, lane = (r >> 3) & 63;
    int ks = (r >> 9) % (K >> 5);
    int nt = r / (512 * (K >> 5));
    int row = nt * 16 + (lane & 15);
    int col = ks * 32 + ((lane >> 4) << 3) + jj;
    float v = W[(long)l * per_l + row * K + col];
    ushort h = f2bf(v);
    hi[idx] = h;
    lo[idx] = f2bf(v - bf2f(h));
}

__global__ void k_head(const float* __restrict__ W_o1, const float* __restrict__ b_o1,
                       const float* __restrict__ W_o2, const float* __restrict__ b_o2,
                       float* __restrict__ Weff, float* __restrict__ beff) {
    int c = threadIdx.x;
    float acc = 0.f;
    for (int j = 0; j < 128; j++) acc += W_o2[j] * W_o1[j * 64 + c];
    Weff[c] = acc;
    if (c == 0) {
        float bb = 0.f;
        for (int j = 0; j < 128; j++) bb += W_o2[j] * b_o1[j];
        beff[0] = bb + b_o2[0];
    }
}

// Fused input projection -> bf16 hi/lo in [b][m][c][n] layout.
__global__ __launch_bounds__(256) void k_inproj_bf(const float* __restrict__ xin,
                                                   const float* __restrict__ W_in,
                                                   const float* __restrict__ b_in,
                                                   ushort* __restrict__ xbf) {
    __shared__ __align__(16) ushort tile[2][64][72];
    int t = threadIdx.x;
    int bid = blockIdx.x;
    int b = bid >> 10, m = (bid >> 2) & 255, n0 = (bid & 3) * 64;
    int c = t & 63, ng = t >> 6;
    long pbase = (long)(b * 256 + m) * 256 + n0;
    float w[12];
#pragma unroll
    for (int d = 0; d < 12; d++) w[d] = W_in[c * 12 + d];
    float bc = b_in[c];
#pragma unroll 4
    for (int i = 0; i < 16; i++) {
        int nl = ng * 16 + i;
        const float* xr = xin + (pbase + nl) * 12;
        float acc = bc;
#pragma unroll
        for (int d = 0; d < 12; d++) acc += xr[d] * w[d];
        ushort hh, ll;
        split(acc, hh, ll);
        tile[0][c][nl] = hh;
        tile[1][c][nl] = ll;
    }
    __syncthreads();
    int c2 = t >> 2, ch = t & 3;
#pragma unroll
    for (int pl = 0; pl < 2; pl++) {
        const ushort* s = &tile[pl][c2][ch * 16];
        u16x8 v0 = *(const u16x8*)s;
        u16x8 v1 = *(const u16x8*)(s + 8);
        ushort* dst = xbf + (long)pl * XPLANE + ((long)(b * 256 + m) * 64 + c2) * 256 + n0 + ch * 16;
        *(u16x8*)dst = v0; *(u16x8*)(dst + 8) = v1;
    }
}

// bf16 transpose: xbf_y [b][m][c][n] -> xbf_x [b][n][c][m].
__global__ __launch_bounds__(256) void k_tx(const ushort* __restrict__ src, ushort* __restrict__ dst) {
    __shared__ __align__(16) ushort tl[64][72];
    int t = threadIdx.x;
    int bid = blockIdx.x;
    int ntile = bid & 3, mt = (bid >> 2) & 3, c = (bid >> 4) & 63, b = (bid >> 10) & 3, pl = bid >> 12;
    int m0 = mt * 64, n0 = ntile * 64;
    const ushort* sp = src + (long)pl * XPLANE;
    ushort* dp = dst + (long)pl * XPLANE;
    {
        int row = t >> 2, ch = (t & 3) * 16;
        const ushort* p = sp + ((long)(b * 256 + m0 + row) * 64 + c) * 256 + n0 + ch;
        u16x8 v0 = *(const u16x8*)p;
        u16x8 v1 = *(const u16x8*)(p + 8);
#pragma unroll
        for (int k = 0; k < 8; k++) tl[ch + k][row] = v0[k];
#pragma unroll
        for (int k = 0; k < 8; k++) tl[ch + 8 + k][row] = v1[k];
    }
    __syncthreads();
    {
        int nrow = t >> 2, mch = (t & 3) * 16;
        const ushort* s = &tl[nrow][mch];
        u16x8 v0 = *(const u16x8*)s;
        u16x8 v1 = *(const u16x8*)(s + 8);
        ushort* p = dp + ((long)(b * 256 + n0 + nrow) * 64 + c) * 256 + m0 + mch;
        *(u16x8*)p = v0; *(u16x8*)(p + 8) = v1;
    }
}

// ---------------- merged spectral kernel ----------------
// grid 1024: blocks 0..511 = y-path: DCT -> mix -> dump Xm_y[b][m][pl][c][y] (bf16 hi/lo, 8 MB)
//            blocks 512..1023 = x-path: DCT -> mix -> iDCT -> h_x[b][n][a=m][c] bf16
__global__ __launch_bounds__(512) void k_spec(const ushort* __restrict__ xbf_y,
                                              const ushort* __restrict__ xbf_x,
                                              const ushort* __restrict__ Tf,
                                              const ushort* __restrict__ Ttf,
                                              const float* __restrict__ wt_y,
                                              const float* __restrict__ wt_x,
                                              ushort* __restrict__ xmy,
                                              ushort* __restrict__ hx) {
    __shared__ float Xs[2][32][68];                    // 17.4 KB
    __shared__ __align__(16) ushort Xmb[2][2][64][40]; // [s][pl][o][y] 20.5 KB
    int t = threadIdx.x;
    int lane = t & 63, wv = t >> 6, l15 = lane & 15, l4 = lane >> 4;
    int bid = blockIdx.x;
    int xpath = bid >> 9;               // 0 = y-path, 1 = x-path (block-uniform)
    int lb = bid & 511;
    int fp = lb & 127, b = lb >> 7;
    int s_ = wv >> 2;
    const ushort* xbf = xpath ? xbf_x : xbf_y;
    const float* wt = xpath ? wt_x : wt_y;

    // ---- DCT (MFMA) ----
    {
        const ushort* xb = xbf + ((long)(b * 256 + fp * 2 + s_)) * 16384;
        f32x4 a0 = {0.f, 0.f, 0.f, 0.f}, a1 = {0.f, 0.f, 0.f, 0.f};
        int c0 = (wv & 3) * 16;
#pragma unroll
        for (int ks = 0; ks < 8; ks++) {
            const ushort* bp = xb + (c0 + l15) * 256 + ks * 32 + l4 * 8;
            bfrag bhi = *(const bfrag*)bp;
            bfrag blo = *(const bfrag*)(bp + XPLANE);
            const ushort* ap0 = Tf + (long)((0 * 8 + ks) * 64 + lane) * 8;
            const ushort* ap1 = Tf + (long)((1 * 8 + ks) * 64 + lane) * 8;
            bfrag a0h = *(const bfrag*)ap0, a0l = *(const bfrag*)(ap0 + 8192);
            bfrag a1h = *(const bfrag*)ap1, a1l = *(const bfrag*)(ap1 + 8192);
            a0 = MFMA(a0h, bhi, a0, 0, 0, 0);
            a0 = MFMA(a0h, blo, a0, 0, 0, 0);
            a0 = MFMA(a0l, bhi, a0, 0, 0, 0);
            a1 = MFMA(a1h, bhi, a1, 0, 0, 0);
            a1 = MFMA(a1h, blo, a1, 0, 0, 0);
            a1 = MFMA(a1l, bhi, a1, 0, 0, 0);
        }
#pragma unroll
        for (int r = 0; r < 4; r++) {
            Xs[s_][l4 * 4 + r][c0 + l15] = a0[r];
            Xs[s_][16 + l4 * 4 + r][c0 + l15] = a1[r];
        }
    }
    __syncthreads();

    // ---- mix (VALU); weight load amortized over both slabs ----
    {
        int og = t & 15, y = t >> 4;   // y in 0..31
        const float* wb = wt + (long)y * 4096 + og * 4;
        f32x4 A0 = {0.f, 0.f, 0.f, 0.f}, A1 = {0.f, 0.f, 0.f, 0.f};
#pragma unroll 8
        for (int i = 0; i < 64; i++) {
            float4 wv4 = *(const float4*)(wb + i * 64);
            float x0 = Xs[0][y][i];
            float x1 = Xs[1][y][i];
            A0.x += x0 * wv4.x; A0.y += x0 * wv4.y; A0.z += x0 * wv4.z; A0.w += x0 * wv4.w;
            A1.x += x1 * wv4.x; A1.y += x1 * wv4.y; A1.z += x1 * wv4.z; A1.w += x1 * wv4.w;
        }
#pragma unroll
        for (int e = 0; e < 4; e++) {
            ushort hh, ll;
            split(A0[e], hh, ll);
            Xmb[0][0][og * 4 + e][y] = hh;
            Xmb[0][1][og * 4 + e][y] = ll;
            split(A1[e], hh, ll);
            Xmb[1][0][og * 4 + e][y] = hh;
            Xmb[1][1][og * 4 + e][y] = ll;
        }
    }
    __syncthreads();

    if (!xpath) {
        // ---- y-path: dump Xmb to global Xm_y[b][m=f][pl][c][y] (8 KB/slab) ----
        int r = t & 255, s2 = t >> 8;
        int pl = r >> 7, c = (r >> 1) & 63, yh = (r & 1) * 16;
        long f2 = fp * 2 + s2;
        ushort* dst = xmy + ((long)(b * 256 + f2) * 2 + pl) * 2048 + c * 32 + yh;
        *(u16x8*)dst = *(const u16x8*)&Xmb[s2][pl][c][yh];
        *(u16x8*)(dst + 8) = *(const u16x8*)&Xmb[s2][pl][c][yh + 8];
        return;
    }

    // ---- x-path iDCT (MFMA) -> h_x[b][n=f][a=m][c] bf16, coalesced ----
    bfrag vbh[4], vbl[4];
#pragma unroll
    for (int ot = 0; ot < 4; ot++) {
        vbh[ot] = *(const bfrag*)(&Xmb[s_][0][ot * 16 + l15][l4 * 8]);
        vbl[ot] = *(const bfrag*)(&Xmb[s_][1][ot * 16 + l15][l4 * 8]);
    }
    int f = fp * 2 + s_;
#pragma unroll
    for (int ai = 0; ai < 4; ai++) {
        int at = (wv & 3) * 4 + ai;
        const ushort* ap = Ttf + (long)(at * 64 + lane) * 8;
        bfrag th = *(const bfrag*)ap, tl_ = *(const bfrag*)(ap + 8192);
#pragma unroll
        for (int ot = 0; ot < 4; ot++) {
            f32x4 acc = {0.f, 0.f, 0.f, 0.f};
            acc = MFMA(th, vbh[ot], acc, 0, 0, 0);
            acc = MFMA(th, vbl[ot], acc, 0, 0, 0);
            acc = MFMA(tl_, vbh[ot], acc, 0, 0, 0);
            int arow = at * 16 + l4 * 4;
            ushort* op = hx + (long)b * 4194304 + (long)f * 16384 + (long)arow * 64 + ot * 16 + l15;
#pragma unroll
            for (int r = 0; r < 4; r++) op[r * 64] = f2bf_hw(acc[r]);
        }
    }
}

// ---------------- FFN via bf16x3 MFMA; h_y reconstructed in-kernel via iDCT ----------------
// R14 structure (proven 607.7 us total). XCD-swizzled blockIdx: groups of 4 blocks
// sharing (b,m) — and hence the same 16 KB xmy row — stay on one XCD's L2.
#define ASW 136   // ushort row stride (128 + 8 pad)
__global__ __launch_bounds__(256) void k_ff(const ushort* __restrict__ xmy,
                                            const ushort* __restrict__ hx,
                                            const ushort* __restrict__ Ttf,
                                            ushort* __restrict__ xbfw,
                                            const ushort* __restrict__ W1hi, const ushort* __restrict__ W1lo,
                                            const float* __restrict__ b1,
                                            const ushort* __restrict__ W2hi, const ushort* __restrict__ W2lo,
                                            const float* __restrict__ b2,
                                            const float* __restrict__ Weff, const float* __restrict__ beff,
                                            float* __restrict__ out, int last) {
    __shared__ __align__(16) float hyt[64][68];        // 17.4 KB
    __shared__ __align__(16) ushort Asb[2][64][ASW];   // 34.8 KB (total 52.2 KB)
    int t = threadIdx.x;
    int lane = t & 63, wv = t >> 6;
    int l15 = lane & 15, l4 = lane >> 4;
    // XCD-aware bijective swizzle (4096 blocks, 8 XCDs): hw-consecutive bids with the
    // same (bid&7) land on one XCD; map them to consecutive logical blocks.
    int bid = blockIdx.x;
    int lb = ((bid & 7) << 9) | (bid >> 3);
    long p0 = (long)lb * 64;
    int b = (int)(p0 >> 16), m = (int)((p0 >> 8) & 255), n0 = (int)(p0 & 255);

    // ---- phase 0: iDCT-y -> hyt (wave wv owns n-rows wv*16..+15) ----
    {
        const ushort* xm = xmy + ((long)(b * 256 + m) * 2) * 2048;
        int at = (n0 >> 4) + wv;
        const ushort* ap = Ttf + (long)(at * 64 + lane) * 8;
        bfrag th = *(const bfrag*)ap, tl_ = *(const bfrag*)(ap + 8192);
#pragma unroll
        for (int ot = 0; ot < 4; ot++) {
            const ushort* xp = xm + (ot * 16 + l15) * 32 + l4 * 8;
            bfrag xh = *(const bfrag*)xp;
            bfrag xl = *(const bfrag*)(xp + 2048);
            f32x4 acc = {0.f, 0.f, 0.f, 0.f};
            acc = MFMA(th, xh, acc, 0, 0, 0);
            acc = MFMA(th, xl, acc, 0, 0, 0);
            acc = MFMA(tl_, xh, acc, 0, 0, 0);
#pragma unroll
            for (int r = 0; r < 4; r++)
                hyt[wv * 16 + l4 * 4 + r][ot * 16 + l15] = acc[r];
        }
    }
    __syncthreads();

    // GEMM1: A = relu(H @ W1^T + b1), H = hyt + bf2f(h_x)
    f32x4 acc1[8];
#pragma unroll
    for (int nt = 0; nt < 8; nt++) acc1[nt] = (f32x4){0.f, 0.f, 0.f, 0.f};
#pragma unroll
    for (int ks = 0; ks < 2; ks++) {
        int px = wv * 16 + l15;
        const float* hp = &hyt[px][ks * 32 + l4 * 8];
        float4 h0 = *(const float4*)hp;
        float4 h1 = *(const float4*)(hp + 4);
        // h_x transposed: pixel (m, n0+px) at [b][n][m][c]
        long xoff = ((long)b * 65536 + (long)(n0 + px) * 256 + m) * 64 + ks * 32 + l4 * 8;
        u16x8 hx8 = *(const u16x8*)(hx + xoff);
        bfrag ahi, alo;
#pragma unroll
        for (int j = 0; j < 8; j++) {
            float v = ((j < 4) ? (&h0.x)[j] : (&h1.x)[j - 4]) + bf2f(hx8[j]);
            ushort hh, ll;
            split(v, hh, ll);
            ahi[j] = (short)hh; alo[j] = (short)ll;
        }
#pragma unroll
        for (int nt = 0; nt < 8; nt++) {
            long off = (long)((nt * 2 + ks) * 64 + lane) * 8;
            bfrag bhi = *(const bfrag*)(W1hi + off);
            bfrag blo = *(const bfrag*)(W1lo + off);
            acc1[nt] = MFMA(ahi, bhi, acc1[nt], 0, 0, 0);
            acc1[nt] = MFMA(ahi, blo, acc1[nt], 0, 0, 0);
            acc1[nt] = MFMA(alo, bhi, acc1[nt], 0, 0, 0);
        }
    }
    // bias + relu + hi/lo split -> Asb
#pragma unroll
    for (int nt = 0; nt < 8; nt++) {
        float bj = b1[nt * 16 + l15];
        int j = nt * 16 + l15;
#pragma unroll
        for (int r = 0; r < 4; r++) {
            float v = fmaxf(acc1[nt][r] + bj, 0.f);
            int px = wv * 16 + l4 * 4 + r;
            ushort hh, ll;
            split(v, hh, ll);
            Asb[0][px][j] = hh;
            Asb[1][px][j] = ll;
        }
    }
    __syncthreads();   // REQUIRED: LDS write->read ordering (R12 race without it)

    // GEMM2: O = A @ W2^T  (A-frags straight from LDS, no conversion)
    f32x4 acc2[4];
#pragma unroll
    for (int nt = 0; nt < 4; nt++) acc2[nt] = (f32x4){0.f, 0.f, 0.f, 0.f};
#pragma unroll
    for (int ks = 0; ks < 4; ks++) {
        bfrag ahi = *(const bfrag*)(&Asb[0][wv * 16 + l15][ks * 32 + l4 * 8]);
        bfrag alo = *(const bfrag*)(&Asb[1][wv * 16 + l15][ks * 32 + l4 * 8]);
#pragma unroll
        for (int nt = 0; nt < 4; nt++) {
            long off = (long)((nt * 4 + ks) * 64 + lane) * 8;
            bfrag bhi = *(const bfrag*)(W2hi + off);
            bfrag blo = *(const bfrag*)(W2lo + off);
            acc2[nt] = MFMA(ahi, bhi, acc2[nt], 0, 0, 0);
            acc2[nt] = MFMA(ahi, blo, acc2[nt], 0, 0, 0);
            acc2[nt] = MFMA(alo, bhi, acc2[nt], 0, 0, 0);
        }
    }

    if (last) {
        float be = beff[0];
#pragma unroll
        for (int r = 0; r < 4; r++) {
            float v = 0.f;
#pragma unroll
            for (int nt = 0; nt < 4; nt++) {
                int c = nt * 16 + l15;
                v += (acc2[nt][r] + b2[c]) * Weff[c];
            }
            v += __shfl_xor(v, 1, 64);
            v += __shfl_xor(v, 2, 64);
            v += __shfl_xor(v, 4, 64);
            v += __shfl_xor(v, 8, 64);
            if (l15 == 0) out[p0 + wv * 16 + l4 * 4 + r] = v + be;
        }
    } else {
        __syncthreads();   // all waves done with their Asb rows
        ushort* tile = &Asb[0][0][0];   // reuse as [2][64][72] x-tile (18.4 KB)
        int c2 = t >> 2, ch = t & 3;
        // stage residual coalesced into tile
#pragma unroll
        for (int pl = 0; pl < 2; pl++) {
            const ushort* src = xbfw + (long)pl * XPLANE + ((long)(b * 256 + m) * 64 + c2) * 256 + n0 + ch * 16;
            u16x8 v0 = *(const u16x8*)src;
            u16x8 v1 = *(const u16x8*)(src + 8);
            ushort* d = tile + (pl * 64 + c2) * 72 + ch * 16;
            *(u16x8*)d = v0; *(u16x8*)(d + 8) = v1;
        }
        __syncthreads();
        // per-thread RMW in LDS (each (c,nl) owned by exactly one thread)
#pragma unroll
        for (int nt = 0; nt < 4; nt++) {
            int c = nt * 16 + l15;
            float bc = b2[c];
#pragma unroll
            for (int r = 0; r < 4; r++) {
                int nl = wv * 16 + l4 * 4 + r;
                float res = bf2f(tile[(0 * 64 + c) * 72 + nl]) + bf2f(tile[(1 * 64 + c) * 72 + nl]);
                float v = res + acc2[nt][r] + bc;
                ushort hh, ll;
                split(v, hh, ll);
                tile[(0 * 64 + c) * 72 + nl] = hh;
                tile[(1 * 64 + c) * 72 + nl] = ll;
            }
        }
        __syncthreads();
        // coalesced store back to xbf_y
#pragma unroll
        for (int pl = 0; pl < 2; pl++) {
            const ushort* s = tile + (pl * 64 + c2) * 72 + ch * 16;
            u16x8 v0 = *(const u16x8*)s;
            u16x8 v1 = *(const u16x8*)(s + 8);
            ushort* dst = xbfw + (long)pl * XPLANE + ((long)(b * 256 + m) * 64 + c2) * 256 + n0 + ch * 16;
            *(u16x8*)dst = v0; *(u16x8*)(dst + 8) = v1;
        }
    }
}

// ---------------- launcher ----------------

extern "C" void kernel_launch(void* const* d_in, const int* in_sizes, int n_in,
                              void* d_out, int out_size, void* d_ws, size_t ws_size,
                              hipStream_t stream) {
    const float* x_in = (const float*)d_in[0];
    const float* W_in = (const float*)d_in[1];
    const float* b_in = (const float*)d_in[2];
    const float* fw0  = (const float*)d_in[3];
    const float* fw1  = (const float*)d_in[4];
    const float* ffW1 = (const float*)d_in[5];
    const float* ffb1 = (const float*)d_in[6];
    const float* ffW2 = (const float*)d_in[7];
    const float* ffb2 = (const float*)d_in[8];
    const float* W_o1 = (const float*)d_in[9];
    const float* b_o1 = (const float*)d_in[10];
    const float* W_o2 = (const float*)d_in[11];
    const float* b_o2 = (const float*)d_in[12];
    float* out = (float*)d_out;

    // workspace layout: ~172 MiB
    float* ws   = (float*)d_ws;
    float* w0t  = ws;                     // 524288
    float* w1t  = w0t + 524288;           // 524288
    float* Weff = w1t + 524288;           // 64
    float* beff = Weff + 64;              // 64
    ushort* xmy = (ushort*)(beff + 64);         // 4194304 ushorts (8 MB): [b][m][pl][c][y]
    ushort* h_x = xmy + 4194304;                // 16777216 ushorts (32 MB)
    ushort* Tfrag  = h_x + 16777216;            // 16384
    ushort* Ttfrag = Tfrag + 16384;             // 16384
    ushort* W1f_hi = Ttfrag + 16384;            // 32768
    ushort* W1f_lo = W1f_hi + 32768;
    ushort* W2f_hi = W1f_lo + 32768;
    ushort* W2f_lo = W2f_hi + 32768;
    ushort* xbf_y  = W2f_lo + 32768;            // 2*16777216 (64 MB)
    ushort* xbf_x  = xbf_y + 2 * XPLANE;        // 2*16777216 (64 MB)

    k_Tboth<<<64, 256, 0, stream>>>(Tfrag, Ttfrag);
    k_wt<<<4096, 256, 0, stream>>>(fw0, fw1, w0t);
    k_wfrag<<<(NLAYERS * HID * CH) / 256, 256, 0, stream>>>(ffW1, W1f_hi, W1f_lo, HID, CH);
    k_wfrag<<<(NLAYERS * CH * HID) / 256, 256, 0, stream>>>(ffW2, W2f_hi, W2f_lo, CH, HID);
    k_head<<<1, 64, 0, stream>>>(W_o1, b_o1, W_o2, b_o2, Weff, beff);
    k_inproj_bf<<<4096, 256, 0, stream>>>(x_in, W_in, b_in, xbf_y);

    for (int l = 0; l < NLAYERS; l++) {
        // transpose: xbf_x[b][n][c][m] from current xbf_y
        k_tx<<<8192, 256, 0, stream>>>(xbf_y, xbf_x);
        // merged spectral: y-blocks -> Xm_y (bf16 hi/lo spectral), x-blocks -> h_x (bf16)
        k_spec<<<1024, 512, 0, stream>>>(xbf_y, xbf_x, Tfrag, Ttfrag,
                                         w0t + (long)l * 131072, w1t + (long)l * 131072,
                                         xmy, h_x);
        // FFN (+ in-kernel iDCT-y) + residual (RMW on xbf_y) (+ head on last layer)
        k_ff<<<4096, 256, 0, stream>>>(xmy, h_x, Ttfrag, xbf_y,
            W1f_hi + (long)l * HID * CH, W1f_lo + (long)l * HID * CH,
            ffb1 + (long)l * HID,
            W2f_hi + (long)l * CH * HID, W2f_lo + (long)l * CH * HID,
            ffb2 + (long)l * CH,
            Weff, beff, out, (l == NLAYERS - 1) ? 1 : 0);
    }
}